// Round 7
// baseline (744.357 us; speedup 1.0000x reference)
//
#include <hip/hip_runtime.h>
#include <hip/hip_bf16.h>
#include <stdint.h>

typedef __bf16 bf16_t;
typedef __bf16 bf16x8 __attribute__((ext_vector_type(8)));
typedef float f32x4 __attribute__((ext_vector_type(4)));
typedef float f32x16 __attribute__((ext_vector_type(16)));

#define BB 4
#define NN 4096
#define DD 384
#define KBLK 64
#define NT (NN / KBLK)             // 64 kv tiles of 64 keys
#define NROWS (BB * NN)            // 16384
#define SCALEC 20.609929155556627f // log2(e)/0.07 ; also the fixed softmax max

// ---------------- Kernel 1: row-normalize -> bf16 ----------------
__global__ __launch_bounds__(256) void norm_kernel(const float* __restrict__ x,
                                                   bf16_t* __restrict__ xn) {
    int row  = blockIdx.x * 4 + (threadIdx.x >> 6);
    int lane = threadIdx.x & 63;
    const float* xr = x + (size_t)row * DD;
    float v[6];
    float ss = 0.f;
#pragma unroll
    for (int j = 0; j < 6; ++j) { v[j] = xr[lane + j * 64]; ss += v[j] * v[j]; }
#pragma unroll
    for (int m = 1; m < 64; m <<= 1) ss += __shfl_xor(ss, m);
    float inv = 1.0f / fmaxf(sqrtf(ss), 1e-12f);
    bf16_t* o = xn + (size_t)row * DD;
#pragma unroll
    for (int j = 0; j < 6; ++j) o[lane + j * 64] = (bf16_t)(v[j] * inv);
}

// ---------------- Kernel 2: transpose-cast x -> xvT (B, D, N) bf16 ----------------
__global__ __launch_bounds__(256) void transpose_kernel(const float* __restrict__ x,
                                                        bf16_t* __restrict__ xvT) {
    int bid = blockIdx.x;
    int dt = bid % (DD / 64);                 // 6
    int nt = (bid / (DD / 64)) % (NN / 64);   // 64
    int b  = bid / ((DD / 64) * (NN / 64));
    __shared__ float tile[64][65];
    int t = threadIdx.x;
    const float* src = x + ((size_t)b * NN + (size_t)nt * 64) * DD + dt * 64;
#pragma unroll
    for (int j = 0; j < 4; ++j) {
        int lin = j * 256 + t;
        int nl = lin >> 4;
        int dc = (lin & 15) * 4;
        const float4 f = *(const float4*)(src + (size_t)nl * DD + dc);
        tile[nl][dc + 0] = f.x; tile[nl][dc + 1] = f.y;
        tile[nl][dc + 2] = f.z; tile[nl][dc + 3] = f.w;
    }
    __syncthreads();
    bf16_t* dst = xvT + ((size_t)b * DD + (size_t)dt * 64) * NN + (size_t)nt * 64;
#pragma unroll
    for (int j = 0; j < 2; ++j) {
        int lin = j * 256 + t;
        int dl = lin >> 3;
        int nc = (lin & 7) * 8;
        bf16x8 v;
#pragma unroll
        for (int jj = 0; jj < 8; ++jj) v[jj] = (bf16_t)tile[nc + jj][dl];
        *(bf16x8*)(dst + (size_t)dl * NN + nc) = v;
    }
}

__device__ __forceinline__ void load_lds16(const void* g, void* l) {
    __builtin_amdgcn_global_load_lds((const __attribute__((address_space(1))) uint32_t*)g,
                                     (__attribute__((address_space(3))) uint32_t*)l,
                                     16, 0, 0);
}

// ---------------- Kernel 3: flash attention ----------------
// QK: mfma_16x16x32, wave w owns q rows w*16..w*16+16, ALL 64 keys.
//     qf[12] = 48 VGPR (was 96) -> VGPR side fits under the 128 cap, no spill.
// PV: mfma_32x32x16, wave w = d-slice of 96 cols (unchanged).
// K LDS (48KB) fragment-linear: 16B slot = (c2h*64 + key), c2h = d-elems/8.
// P LDS (16KB): row q stride 256B, byte = q*256 + ((key*2) ^ ((q&15)<<4)).
// V: direct global->reg, pipelined in 12-VGPR slices.
template <bool SPLIT>
__global__ __launch_bounds__(256, 2) void attn_kernel(const float* __restrict__ x,
                                                      const bf16_t* __restrict__ xn,
                                                      const bf16_t* __restrict__ xvT,
                                                      float* __restrict__ out,
                                                      float* __restrict__ Opart,
                                                      float* __restrict__ lpart) {
    constexpr int TPS = SPLIT ? (NT / 2) : NT;
    __shared__ __align__(16) char Ks[49152];      // K tile, fragment-linear
    __shared__ __align__(16) char Pb[16384];      // P, swizzled rows of 256B

    const int tid = threadIdx.x;
    const int w = tid >> 6, l = tid & 63;
    const int l31 = l & 31, hi = l >> 5;          // PV roles
    const int lo16 = l & 15, g4 = l >> 4;         // QK roles (16-lane groups)

    const int bid = blockIdx.x;
    int b, qi, s_idx;
    if (SPLIT) {  // xcd = bid&7 -> (batch, split): 1.5MB K + 1.5MB V per XCD L2
        b = (bid & 7) >> 1; s_idx = bid & 1; qi = bid >> 3;
    } else {
        b = (bid >> 1) & 3; s_idx = 0; qi = (bid >> 3) | ((bid & 1) << 5);
    }
    const int kt0 = s_idx * TPS;
    const int qrow0 = b * NN + qi * 64;

    const char* xnb  = (const char*)xn;
    const char* xvTb = (const char*)xvT;
    char* Ksb = (char*)Ks;
    char* Pbb = (char*)Pb;

    // --- Q fragments in regs: 12 chunks of K=32 (rows w*16+lo16) ---
    const bf16_t* qp = xn + (size_t)(qrow0 + w * 16 + lo16) * DD + g4 * 8;
    bf16x8 qf[12];
#pragma unroll
    for (int c = 0; c < 12; ++c) qf[c] = *(const bf16x8*)(qp + c * 32);

    f32x16 O0, O1, O2, O3, O4, O5;   // O(3*g2+dt): rows g2*32.., cols w*96+dt*32..
    O0 = 0.f; O1 = 0.f; O2 = 0.f; O3 = 0.f; O4 = 0.f; O5 = 0.f;
    float lacc = 0.f;                 // row-sum partial (row tid>>2, keys (tid&3)*16..+16)

#define STAGE_K(KT) { \
    const size_t kg = ((size_t)b * NN + (size_t)(KT) * KBLK) * (DD * 2); \
    _Pragma("unroll") \
    for (int i = 0; i < 12; ++i) { \
        int idx = i * 256 + tid; int key = idx & 63; int c2h = idx >> 6; \
        load_lds16(xnb + kg + (size_t)key * (DD * 2) + c2h * 16, \
                   (void*)(Ksb + (size_t)(i * 256 + (w << 6)) * 16)); \
    } }

    STAGE_K(kt0);

    // per-lane constants
    const char* kB = Ksb + (size_t)g4 * 1024 + lo16 * 16;  // QK B-frag base
    const int psw = (l31 & 15) << 4;                       // PV A read swizzle
    const int rsrow = tid >> 2, rsseg = tid & 3;           // row-sum role
    const int rswz = (rsrow & 15) << 4;
    const int qrow16 = w * 16 + g4 * 4;                    // this lane's P-write rows

#define VLD(DST, KC) { \
    _Pragma("unroll") \
    for (int dt = 0; dt < 3; ++dt) \
        DST[dt] = *(const bf16x8*)(vB + (size_t)dt * 32 * (NN * 2) + (KC) * 32); }

#define PV_STEP(VF, KC) { \
    bf16x8 pa0 = *(const bf16x8*)(Pbb + (l31) * 256 + (((KC) * 32 + hi * 16) ^ psw)); \
    bf16x8 pa1 = *(const bf16x8*)(Pbb + (32 + l31) * 256 + (((KC) * 32 + hi * 16) ^ psw)); \
    O0 = __builtin_amdgcn_mfma_f32_32x32x16_bf16(pa0, VF[0], O0, 0, 0, 0); \
    O1 = __builtin_amdgcn_mfma_f32_32x32x16_bf16(pa0, VF[1], O1, 0, 0, 0); \
    O2 = __builtin_amdgcn_mfma_f32_32x32x16_bf16(pa0, VF[2], O2, 0, 0, 0); \
    O3 = __builtin_amdgcn_mfma_f32_32x32x16_bf16(pa1, VF[0], O3, 0, 0, 0); \
    O4 = __builtin_amdgcn_mfma_f32_32x32x16_bf16(pa1, VF[1], O4, 0, 0, 0); \
    O5 = __builtin_amdgcn_mfma_f32_32x32x16_bf16(pa1, VF[2], O5, 0, 0, 0); }

// softmax+P-write for one 16-key block kb from accumulator SS
#define SM_STEP(SS, KB) { \
    _Pragma("unroll") \
    for (int r = 0; r < 4; ++r) { \
        float p = __builtin_amdgcn_exp2f(fmaf(SS[r], SCALEC, -SCALEC)); \
        int q = qrow16 + r; \
        int off = q * 256 + ((((KB) * 16 + lo16) * 2) ^ ((q & 15) << 4)); \
        *(bf16_t*)(Pbb + off) = (bf16_t)p; \
    } }

    for (int t = 0; t < TPS; ++t) {
        const int kt = kt0 + t;
        const char* vB = xvTb + (((size_t)(b * DD + w * 96 + l31) * NN)
                                 + (size_t)kt * KBLK + hi * 8) * 2;
        // --- top barrier: K[t] staging complete everywhere ---
        asm volatile("s_waitcnt vmcnt(0)" ::: "memory");
        __builtin_amdgcn_sched_barrier(0);
        __builtin_amdgcn_s_barrier();
        __builtin_amdgcn_sched_barrier(0);

        // --- QK^T: S[16q x 64k] = 48 x mfma_16x16x32 (4 indep accum chains) ---
        f32x4 s0, s1, s2, s3;
        s0 = 0.f; s1 = 0.f; s2 = 0.f; s3 = 0.f;
#pragma unroll
        for (int c = 0; c < 12; ++c) {
            const char* kc = kB + c * 4096;
            s0 = __builtin_amdgcn_mfma_f32_16x16x32_bf16(qf[c], *(const bf16x8*)(kc),       s0, 0, 0, 0);
            s1 = __builtin_amdgcn_mfma_f32_16x16x32_bf16(qf[c], *(const bf16x8*)(kc + 256), s1, 0, 0, 0);
            s2 = __builtin_amdgcn_mfma_f32_16x16x32_bf16(qf[c], *(const bf16x8*)(kc + 512), s2, 0, 0, 0);
            s3 = __builtin_amdgcn_mfma_f32_16x16x32_bf16(qf[c], *(const bf16x8*)(kc + 768), s3, 0, 0, 0);
        }

        __builtin_amdgcn_sched_barrier(0);
        __builtin_amdgcn_s_barrier();      // QK reads retired -> K buf reusable
        __builtin_amdgcn_sched_barrier(0);

        // --- issue K[t+1] staging (gload_lds: zero VGPR cost) ---
        {
            int ktn = kt + 1; if (ktn > NT - 1) ktn = NT - 1;
            STAGE_K(ktn);
        }
        __builtin_amdgcn_sched_barrier(0);

        // --- V slice kc0 issued here: covered by softmax+P-write+barrier ---
        bf16x8 vfA[3], vfB[3];
        VLD(vfA, 0);

        // --- fixed-max softmax + P writes (swizzled) ---
        SM_STEP(s0, 0); SM_STEP(s1, 1); SM_STEP(s2, 2); SM_STEP(s3, 3);
        asm volatile("s_waitcnt lgkmcnt(0)" ::: "memory");
        __builtin_amdgcn_sched_barrier(0);
        __builtin_amdgcn_s_barrier();      // P visible block-wide
        __builtin_amdgcn_sched_barrier(0);

        // --- V slice kc1; then denominator row-sum (covers kc1 latency) ---
        VLD(vfB, 1);
        {
            const char* rb = Pbb + rsrow * 256;
            bf16x8 a = *(const bf16x8*)(rb + ((rsseg * 32) ^ rswz));
            bf16x8 c = *(const bf16x8*)(rb + ((rsseg * 32 + 16) ^ rswz));
            float ps = 0.f;
#pragma unroll
            for (int e = 0; e < 8; ++e) ps += (float)a[e] + (float)c[e];
            lacc += ps;
        }

        // --- PV pipelined: compute kc while loading kc+2 ---
        PV_STEP(vfA, 0);
        VLD(vfA, 2);
        PV_STEP(vfB, 1);
        VLD(vfB, 3);
        PV_STEP(vfA, 2);
        PV_STEP(vfB, 3);
    }
#undef STAGE_K
#undef VLD
#undef PV_STEP
#undef SM_STEP

    // --- finalize denominator: 4 threads per row ---
    lacc += __shfl_xor(lacc, 1);
    lacc += __shfl_xor(lacc, 2);          // all 4 threads of a row hold the row sum

    if (SPLIT) {
        if ((tid & 3) == 0) lpart[(size_t)s_idx * NROWS + qrow0 + rsrow] = lacc;
        float* Ob = Opart + (size_t)s_idx * NROWS * DD;
        const f32x16* Os[6] = {&O0, &O1, &O2, &O3, &O4, &O5};
#pragma unroll
        for (int g2 = 0; g2 < 2; ++g2) {
#pragma unroll
            for (int dt = 0; dt < 3; ++dt) {
                const f32x16& Ot = *Os[g2 * 3 + dt];
                int dcol = w * 96 + dt * 32 + l31;
#pragma unroll
                for (int r = 0; r < 16; ++r) {
                    int q = g2 * 32 + 4 * hi + (r & 3) + 8 * (r >> 2);
                    Ob[(size_t)(qrow0 + q) * DD + dcol] = Ot[r];
                }
            }
        }
    } else {
        __builtin_amdgcn_s_barrier();
        float* lb = (float*)Pbb;           // P dead; reuse as l buffer
        if ((tid & 3) == 0) lb[rsrow] = lacc;
        asm volatile("s_waitcnt lgkmcnt(0)" ::: "memory");
        __builtin_amdgcn_s_barrier();
        const f32x16* Os[6] = {&O0, &O1, &O2, &O3, &O4, &O5};
#pragma unroll
        for (int g2 = 0; g2 < 2; ++g2) {
#pragma unroll
            for (int dt = 0; dt < 3; ++dt) {
                const f32x16& Ot = *Os[g2 * 3 + dt];
                int dcol = w * 96 + dt * 32 + l31;
#pragma unroll
                for (int r = 0; r < 16; ++r) {
                    int q = g2 * 32 + 4 * hi + (r & 3) + 8 * (r >> 2);
                    size_t idx = (size_t)(qrow0 + q) * DD + dcol;
                    out[idx] = x[idx] + Ot[r] * (0.3f / lb[q]);
                }
            }
        }
    }
}

// ---------------- Kernel 4: merge 2 splits + residual ----------------
__global__ __launch_bounds__(256) void merge_kernel(const float* __restrict__ x,
                                                    const float* __restrict__ Opart,
                                                    const float* __restrict__ lpart,
                                                    float* __restrict__ out) {
    int row  = blockIdx.x * 4 + (threadIdx.x >> 6);
    int lane = threadIdx.x & 63;
    float lsum = lpart[row] + lpart[NROWS + row];
    float inv = 0.3f / lsum;
    size_t base = (size_t)row * DD;
    const float* O0 = Opart + base;
    const float* O1 = Opart + (size_t)NROWS * DD + base;
#pragma unroll
    for (int j = 0; j < 6; ++j) {
        int d = lane + j * 64;
        out[base + d] = x[base + d] + (O0[d] + O1[d]) * inv;
    }
}

extern "C" void kernel_launch(void* const* d_in, const int* in_sizes, int n_in,
                              void* d_out, int out_size, void* d_ws, size_t ws_size,
                              hipStream_t stream) {
    const float* x = (const float*)d_in[0];
    float* out = (float*)d_out;
    char* ws = (char*)d_ws;

    const size_t xn_bytes = (size_t)BB * NN * DD * 2;           // 12.58 MB
    bf16_t* xn  = (bf16_t*)ws;
    bf16_t* xvT = (bf16_t*)(ws + xn_bytes);
    float* Opart = (float*)(ws + 2 * xn_bytes);
    const size_t Opart_bytes = (size_t)2 * NROWS * DD * 4;      // 50.3 MB
    float* lpart = (float*)(ws + 2 * xn_bytes + Opart_bytes);
    const size_t need2 = 2 * xn_bytes + Opart_bytes + (size_t)2 * NROWS * 4;

    norm_kernel<<<(BB * NN) / 4, 256, 0, stream>>>(x, xn);
    transpose_kernel<<<BB * (NN / 64) * (DD / 64), 256, 0, stream>>>(x, xvT);
    if (ws_size >= need2) {
        attn_kernel<true><<<512, 256, 0, stream>>>(x, xn, xvT, out, Opart, lpart);
        merge_kernel<<<NROWS / 4, 256, 0, stream>>>(x, Opart, lpart, out);
    } else {
        attn_kernel<false><<<256, 256, 0, stream>>>(x, xn, xvT, out, nullptr, nullptr);
    }
}

// Round 9
// 729.750 us; speedup vs baseline: 1.0200x; 1.0200x over previous
//
#include <hip/hip_runtime.h>
#include <hip/hip_bf16.h>
#include <stdint.h>

typedef __bf16 bf16_t;
typedef __bf16 bf16x8 __attribute__((ext_vector_type(8)));
typedef float f32x4 __attribute__((ext_vector_type(4)));
typedef float f32x16 __attribute__((ext_vector_type(16)));

#define BB 4
#define NN 4096
#define DD 384
#define KBLK 64
#define NT (NN / KBLK)             // 64 kv tiles of 64 keys
#define NROWS (BB * NN)            // 16384
#define SCALEC 20.609929155556627f // log2(e)/0.07 ; also the fixed softmax max

// ---------------- Kernel 1: row-normalize -> bf16 ----------------
__global__ __launch_bounds__(256) void norm_kernel(const float* __restrict__ x,
                                                   bf16_t* __restrict__ xn) {
    int row  = blockIdx.x * 4 + (threadIdx.x >> 6);
    int lane = threadIdx.x & 63;
    const float* xr = x + (size_t)row * DD;
    float v[6];
    float ss = 0.f;
#pragma unroll
    for (int j = 0; j < 6; ++j) { v[j] = xr[lane + j * 64]; ss += v[j] * v[j]; }
#pragma unroll
    for (int m = 1; m < 64; m <<= 1) ss += __shfl_xor(ss, m);
    float inv = 1.0f / fmaxf(sqrtf(ss), 1e-12f);
    bf16_t* o = xn + (size_t)row * DD;
#pragma unroll
    for (int j = 0; j < 6; ++j) o[lane + j * 64] = (bf16_t)(v[j] * inv);
}

// ---------------- Kernel 2: transpose-cast x -> xvT (B, D, N) bf16 ----------------
__global__ __launch_bounds__(256) void transpose_kernel(const float* __restrict__ x,
                                                        bf16_t* __restrict__ xvT) {
    int bid = blockIdx.x;
    int dt = bid % (DD / 64);                 // 6
    int nt = (bid / (DD / 64)) % (NN / 64);   // 64
    int b  = bid / ((DD / 64) * (NN / 64));
    __shared__ float tile[64][65];
    int t = threadIdx.x;
    const float* src = x + ((size_t)b * NN + (size_t)nt * 64) * DD + dt * 64;
#pragma unroll
    for (int j = 0; j < 4; ++j) {
        int lin = j * 256 + t;
        int nl = lin >> 4;
        int dc = (lin & 15) * 4;
        const float4 f = *(const float4*)(src + (size_t)nl * DD + dc);
        tile[nl][dc + 0] = f.x; tile[nl][dc + 1] = f.y;
        tile[nl][dc + 2] = f.z; tile[nl][dc + 3] = f.w;
    }
    __syncthreads();
    bf16_t* dst = xvT + ((size_t)b * DD + (size_t)dt * 64) * NN + (size_t)nt * 64;
#pragma unroll
    for (int j = 0; j < 2; ++j) {
        int lin = j * 256 + t;
        int dl = lin >> 3;
        int nc = (lin & 7) * 8;
        bf16x8 v;
#pragma unroll
        for (int jj = 0; jj < 8; ++jj) v[jj] = (bf16_t)tile[nc + jj][dl];
        *(bf16x8*)(dst + (size_t)dl * NN + nc) = v;
    }
}

__device__ __forceinline__ void load_lds16(const void* g, void* l) {
    __builtin_amdgcn_global_load_lds((const __attribute__((address_space(1))) uint32_t*)g,
                                     (__attribute__((address_space(3))) uint32_t*)l,
                                     16, 0, 0);
}

// ---------------- Kernel 3: flash attention ----------------
// Identical to round 7 EXCEPT: epilogues no longer take addresses of the O
// accumulators (no f32x16* array). Rule #20: address-taken accumulators risk
// alloca/scratch-backing -> in-loop MFMA C round-trips through scratch.
template <bool SPLIT>
__global__ __launch_bounds__(256, 2) void attn_kernel(const float* __restrict__ x,
                                                      const bf16_t* __restrict__ xn,
                                                      const bf16_t* __restrict__ xvT,
                                                      float* __restrict__ out,
                                                      float* __restrict__ Opart,
                                                      float* __restrict__ lpart) {
    constexpr int TPS = SPLIT ? (NT / 2) : NT;
    __shared__ __align__(16) char Ks[49152];      // K tile, fragment-linear
    __shared__ __align__(16) char Pb[16384];      // P, swizzled rows of 256B

    const int tid = threadIdx.x;
    const int w = tid >> 6, l = tid & 63;
    const int l31 = l & 31, hi = l >> 5;          // PV roles
    const int lo16 = l & 15, g4 = l >> 4;         // QK roles (16-lane groups)

    const int bid = blockIdx.x;
    int b, qi, s_idx;
    if (SPLIT) {  // xcd = bid&7 -> (batch, split): 1.5MB K + 1.5MB V per XCD L2
        b = (bid & 7) >> 1; s_idx = bid & 1; qi = bid >> 3;
    } else {
        b = (bid >> 1) & 3; s_idx = 0; qi = (bid >> 3) | ((bid & 1) << 5);
    }
    const int kt0 = s_idx * TPS;
    const int qrow0 = b * NN + qi * 64;

    const char* xnb  = (const char*)xn;
    const char* xvTb = (const char*)xvT;
    char* Ksb = (char*)Ks;
    char* Pbb = (char*)Pb;

    // --- Q fragments in regs: 12 chunks of K=32 (rows w*16+lo16) ---
    const bf16_t* qp = xn + (size_t)(qrow0 + w * 16 + lo16) * DD + g4 * 8;
    bf16x8 qf[12];
#pragma unroll
    for (int c = 0; c < 12; ++c) qf[c] = *(const bf16x8*)(qp + c * 32);

    f32x16 O0, O1, O2, O3, O4, O5;   // O(3*g2+dt): rows g2*32.., cols w*96+dt*32..
    O0 = 0.f; O1 = 0.f; O2 = 0.f; O3 = 0.f; O4 = 0.f; O5 = 0.f;
    float lacc = 0.f;                 // row-sum partial (row tid>>2, keys (tid&3)*16..+16)

#define STAGE_K(KT) { \
    const size_t kg = ((size_t)b * NN + (size_t)(KT) * KBLK) * (DD * 2); \
    _Pragma("unroll") \
    for (int i = 0; i < 12; ++i) { \
        int idx = i * 256 + tid; int key = idx & 63; int c2h = idx >> 6; \
        load_lds16(xnb + kg + (size_t)key * (DD * 2) + c2h * 16, \
                   (void*)(Ksb + (size_t)(i * 256 + (w << 6)) * 16)); \
    } }

    STAGE_K(kt0);

    // per-lane constants
    const char* kB = Ksb + (size_t)g4 * 1024 + lo16 * 16;  // QK B-frag base
    const int psw = (l31 & 15) << 4;                       // PV A read swizzle
    const int rsrow = tid >> 2, rsseg = tid & 3;           // row-sum role
    const int rswz = (rsrow & 15) << 4;
    const int qrow16 = w * 16 + g4 * 4;                    // this lane's P-write rows

#define VLD(DST, KC) { \
    _Pragma("unroll") \
    for (int dt = 0; dt < 3; ++dt) \
        DST[dt] = *(const bf16x8*)(vB + (size_t)dt * 32 * (NN * 2) + (KC) * 32); }

#define PV_STEP(VF, KC) { \
    bf16x8 pa0 = *(const bf16x8*)(Pbb + (l31) * 256 + (((KC) * 32 + hi * 16) ^ psw)); \
    bf16x8 pa1 = *(const bf16x8*)(Pbb + (32 + l31) * 256 + (((KC) * 32 + hi * 16) ^ psw)); \
    O0 = __builtin_amdgcn_mfma_f32_32x32x16_bf16(pa0, VF[0], O0, 0, 0, 0); \
    O1 = __builtin_amdgcn_mfma_f32_32x32x16_bf16(pa0, VF[1], O1, 0, 0, 0); \
    O2 = __builtin_amdgcn_mfma_f32_32x32x16_bf16(pa0, VF[2], O2, 0, 0, 0); \
    O3 = __builtin_amdgcn_mfma_f32_32x32x16_bf16(pa1, VF[0], O3, 0, 0, 0); \
    O4 = __builtin_amdgcn_mfma_f32_32x32x16_bf16(pa1, VF[1], O4, 0, 0, 0); \
    O5 = __builtin_amdgcn_mfma_f32_32x32x16_bf16(pa1, VF[2], O5, 0, 0, 0); }

// softmax+P-write for one 16-key block kb from accumulator SS
#define SM_STEP(SS, KB) { \
    _Pragma("unroll") \
    for (int r = 0; r < 4; ++r) { \
        float p = __builtin_amdgcn_exp2f(fmaf(SS[r], SCALEC, -SCALEC)); \
        int q = qrow16 + r; \
        int off = q * 256 + ((((KB) * 16 + lo16) * 2) ^ ((q & 15) << 4)); \
        *(bf16_t*)(Pbb + off) = (bf16_t)p; \
    } }

    for (int t = 0; t < TPS; ++t) {
        const int kt = kt0 + t;
        const char* vB = xvTb + (((size_t)(b * DD + w * 96 + l31) * NN)
                                 + (size_t)kt * KBLK + hi * 8) * 2;
        // --- top barrier: K[t] staging complete everywhere ---
        asm volatile("s_waitcnt vmcnt(0)" ::: "memory");
        __builtin_amdgcn_sched_barrier(0);
        __builtin_amdgcn_s_barrier();
        __builtin_amdgcn_sched_barrier(0);

        // --- QK^T: S[16q x 64k] = 48 x mfma_16x16x32 (4 indep accum chains) ---
        f32x4 s0, s1, s2, s3;
        s0 = 0.f; s1 = 0.f; s2 = 0.f; s3 = 0.f;
#pragma unroll
        for (int c = 0; c < 12; ++c) {
            const char* kc = kB + c * 4096;
            s0 = __builtin_amdgcn_mfma_f32_16x16x32_bf16(qf[c], *(const bf16x8*)(kc),       s0, 0, 0, 0);
            s1 = __builtin_amdgcn_mfma_f32_16x16x32_bf16(qf[c], *(const bf16x8*)(kc + 256), s1, 0, 0, 0);
            s2 = __builtin_amdgcn_mfma_f32_16x16x32_bf16(qf[c], *(const bf16x8*)(kc + 512), s2, 0, 0, 0);
            s3 = __builtin_amdgcn_mfma_f32_16x16x32_bf16(qf[c], *(const bf16x8*)(kc + 768), s3, 0, 0, 0);
        }

        __builtin_amdgcn_sched_barrier(0);
        __builtin_amdgcn_s_barrier();      // QK reads retired -> K buf reusable
        __builtin_amdgcn_sched_barrier(0);

        // --- issue K[t+1] staging (gload_lds: zero VGPR cost) ---
        {
            int ktn = kt + 1; if (ktn > NT - 1) ktn = NT - 1;
            STAGE_K(ktn);
        }
        __builtin_amdgcn_sched_barrier(0);

        // --- V slice kc0 issued here: covered by softmax+P-write+barrier ---
        bf16x8 vfA[3], vfB[3];
        VLD(vfA, 0);

        // --- fixed-max softmax + P writes (swizzled) ---
        SM_STEP(s0, 0); SM_STEP(s1, 1); SM_STEP(s2, 2); SM_STEP(s3, 3);
        asm volatile("s_waitcnt lgkmcnt(0)" ::: "memory");
        __builtin_amdgcn_sched_barrier(0);
        __builtin_amdgcn_s_barrier();      // P visible block-wide
        __builtin_amdgcn_sched_barrier(0);

        // --- V slice kc1; then denominator row-sum (covers kc1 latency) ---
        VLD(vfB, 1);
        {
            const char* rb = Pbb + rsrow * 256;
            bf16x8 a = *(const bf16x8*)(rb + ((rsseg * 32) ^ rswz));
            bf16x8 c = *(const bf16x8*)(rb + ((rsseg * 32 + 16) ^ rswz));
            float ps = 0.f;
#pragma unroll
            for (int e = 0; e < 8; ++e) ps += (float)a[e] + (float)c[e];
            lacc += ps;
        }

        // --- PV pipelined: compute kc while loading kc+2 ---
        PV_STEP(vfA, 0);
        VLD(vfA, 2);
        PV_STEP(vfB, 1);
        VLD(vfB, 3);
        PV_STEP(vfA, 2);
        PV_STEP(vfB, 3);
    }
#undef STAGE_K
#undef VLD
#undef PV_STEP
#undef SM_STEP

    // --- finalize denominator: 4 threads per row ---
    lacc += __shfl_xor(lacc, 1);
    lacc += __shfl_xor(lacc, 2);          // all 4 threads of a row hold the row sum

// store one 32x32 accumulator block to Opart (named O reg, NO address-taking)
#define STORE_PART(OT, G2, DT) { \
    int dcol = w * 96 + (DT) * 32 + l31; \
    _Pragma("unroll") \
    for (int r = 0; r < 16; ++r) { \
        int q = (G2) * 32 + 4 * hi + (r & 3) + 8 * (r >> 2); \
        Ob[(size_t)(qrow0 + q) * DD + dcol] = OT[r]; \
    } }

#define STORE_DIRECT(OT, G2, DT) { \
    int dcol = w * 96 + (DT) * 32 + l31; \
    _Pragma("unroll") \
    for (int r = 0; r < 16; ++r) { \
        int q = (G2) * 32 + 4 * hi + (r & 3) + 8 * (r >> 2); \
        size_t idx = (size_t)(qrow0 + q) * DD + dcol; \
        out[idx] = x[idx] + OT[r] * (0.3f / lb[q]); \
    } }

    if (SPLIT) {
        if ((tid & 3) == 0) lpart[(size_t)s_idx * NROWS + qrow0 + rsrow] = lacc;
        float* Ob = Opart + (size_t)s_idx * NROWS * DD;
        STORE_PART(O0, 0, 0) STORE_PART(O1, 0, 1) STORE_PART(O2, 0, 2)
        STORE_PART(O3, 1, 0) STORE_PART(O4, 1, 1) STORE_PART(O5, 1, 2)
    } else {
        __builtin_amdgcn_s_barrier();
        float* lb = (float*)Pbb;           // P dead; reuse as l buffer
        if ((tid & 3) == 0) lb[rsrow] = lacc;
        asm volatile("s_waitcnt lgkmcnt(0)" ::: "memory");
        __builtin_amdgcn_s_barrier();
        STORE_DIRECT(O0, 0, 0) STORE_DIRECT(O1, 0, 1) STORE_DIRECT(O2, 0, 2)
        STORE_DIRECT(O3, 1, 0) STORE_DIRECT(O4, 1, 1) STORE_DIRECT(O5, 1, 2)
    }
#undef STORE_PART
#undef STORE_DIRECT
}

// ---------------- Kernel 4: merge 2 splits + residual ----------------
__global__ __launch_bounds__(256) void merge_kernel(const float* __restrict__ x,
                                                    const float* __restrict__ Opart,
                                                    const float* __restrict__ lpart,
                                                    float* __restrict__ out) {
    int row  = blockIdx.x * 4 + (threadIdx.x >> 6);
    int lane = threadIdx.x & 63;
    float lsum = lpart[row] + lpart[NROWS + row];
    float inv = 0.3f / lsum;
    size_t base = (size_t)row * DD;
    const float* O0 = Opart + base;
    const float* O1 = Opart + (size_t)NROWS * DD + base;
#pragma unroll
    for (int j = 0; j < 6; ++j) {
        int d = lane + j * 64;
        out[base + d] = x[base + d] + (O0[d] + O1[d]) * inv;
    }
}

extern "C" void kernel_launch(void* const* d_in, const int* in_sizes, int n_in,
                              void* d_out, int out_size, void* d_ws, size_t ws_size,
                              hipStream_t stream) {
    const float* x = (const float*)d_in[0];
    float* out = (float*)d_out;
    char* ws = (char*)d_ws;

    const size_t xn_bytes = (size_t)BB * NN * DD * 2;           // 12.58 MB
    bf16_t* xn  = (bf16_t*)ws;
    bf16_t* xvT = (bf16_t*)(ws + xn_bytes);
    float* Opart = (float*)(ws + 2 * xn_bytes);
    const size_t Opart_bytes = (size_t)2 * NROWS * DD * 4;      // 50.3 MB
    float* lpart = (float*)(ws + 2 * xn_bytes + Opart_bytes);
    const size_t need2 = 2 * xn_bytes + Opart_bytes + (size_t)2 * NROWS * 4;

    norm_kernel<<<(BB * NN) / 4, 256, 0, stream>>>(x, xn);
    transpose_kernel<<<BB * (NN / 64) * (DD / 64), 256, 0, stream>>>(x, xvT);
    if (ws_size >= need2) {
        attn_kernel<true><<<512, 256, 0, stream>>>(x, xn, xvT, out, Opart, lpart);
        merge_kernel<<<NROWS / 4, 256, 0, stream>>>(x, Opart, lpart, out);
    } else {
        attn_kernel<false><<<256, 256, 0, stream>>>(x, xn, xvT, out, nullptr, nullptr);
    }
}

// Round 11
// 279.940 us; speedup vs baseline: 2.6590x; 2.6068x over previous
//
#include <hip/hip_runtime.h>
#include <hip/hip_bf16.h>
#include <stdint.h>

typedef __bf16 bf16_t;
typedef __bf16 bf16x8 __attribute__((ext_vector_type(8)));
typedef float f32x4 __attribute__((ext_vector_type(4)));

#define BB 4
#define NN 4096
#define DD 384
#define KBLK 32
#define NKT (NN / KBLK)            // 128 kv tiles of 32 keys
#define NROWS (BB * NN)            // 16384
#define SCALEC 20.609929155556627f // log2(e)/0.07 ; also the fixed softmax max

// ---------------- Kernel 1: row-normalize -> bf16 ----------------
__global__ __launch_bounds__(256) void norm_kernel(const float* __restrict__ x,
                                                   bf16_t* __restrict__ xn) {
    int row  = blockIdx.x * 4 + (threadIdx.x >> 6);
    int lane = threadIdx.x & 63;
    const float* xr = x + (size_t)row * DD;
    float v[6];
    float ss = 0.f;
#pragma unroll
    for (int j = 0; j < 6; ++j) { v[j] = xr[lane + j * 64]; ss += v[j] * v[j]; }
#pragma unroll
    for (int m = 1; m < 64; m <<= 1) ss += __shfl_xor(ss, m);
    float inv = 1.0f / fmaxf(sqrtf(ss), 1e-12f);
    bf16_t* o = xn + (size_t)row * DD;
#pragma unroll
    for (int j = 0; j < 6; ++j) o[lane + j * 64] = (bf16_t)(v[j] * inv);
}

// ---------------- Kernel 2: transpose-cast x -> xvT (B, D, N) bf16 ----------------
__global__ __launch_bounds__(256) void transpose_kernel(const float* __restrict__ x,
                                                        bf16_t* __restrict__ xvT) {
    int bid = blockIdx.x;
    int dt = bid % (DD / 64);                 // 6
    int nt = (bid / (DD / 64)) % (NN / 64);   // 64
    int b  = bid / ((DD / 64) * (NN / 64));
    __shared__ float tile[64][65];
    int t = threadIdx.x;
    const float* src = x + ((size_t)b * NN + (size_t)nt * 64) * DD + dt * 64;
#pragma unroll
    for (int j = 0; j < 4; ++j) {
        int lin = j * 256 + t;
        int nl = lin >> 4;
        int dc = (lin & 15) * 4;
        const float4 f = *(const float4*)(src + (size_t)nl * DD + dc);
        tile[nl][dc + 0] = f.x; tile[nl][dc + 1] = f.y;
        tile[nl][dc + 2] = f.z; tile[nl][dc + 3] = f.w;
    }
    __syncthreads();
    bf16_t* dst = xvT + ((size_t)b * DD + (size_t)dt * 64) * NN + (size_t)nt * 64;
#pragma unroll
    for (int j = 0; j < 2; ++j) {
        int lin = j * 256 + t;
        int dl = lin >> 3;
        int nc = (lin & 7) * 8;
        bf16x8 v;
#pragma unroll
        for (int jj = 0; jj < 8; ++jj) v[jj] = (bf16_t)tile[nc + jj][dl];
        *(bf16x8*)(dst + (size_t)dl * NN + nc) = v;
    }
}

__device__ __forceinline__ void load_lds16(const void* g, void* l) {
    __builtin_amdgcn_global_load_lds((const __attribute__((address_space(1))) uint32_t*)g,
                                     (__attribute__((address_space(3))) uint32_t*)l,
                                     16, 0, 0);
}

// ---------------- Kernel 3: flash attention (round-1 structure + counted-vmcnt pipeline) ----------------
// KBLK=32, 16x16x32 MFMAs. Wave w owns q rows qt*64 + w*16 .. +16.
// K double-buffered LDS (2x24KB), fragment-linear; V LDS (24KB) shared block-wide;
// P per-wave 1KB. Per-tile vmem queue (per wave): [K[t] 6][V[t] 6][K[t+1] 6];
// waits: vmcnt(12) at top (K[t] done), vmcnt(6) mid (V[t] done), NEVER 0 in loop.
template <int S, bool DIRECT>
__global__ __launch_bounds__(256, 2) void attn_kernel(const float* __restrict__ x,
                                                      const bf16_t* __restrict__ xn,
                                                      const bf16_t* __restrict__ xvT,
                                                      float* __restrict__ out,
                                                      float* __restrict__ Opart,
                                                      float* __restrict__ lpart) {
    constexpr int TPS = NKT / S;
    __shared__ __align__(16) char Ks[2][24576];
    __shared__ __align__(16) char VL[24576];
    __shared__ __align__(16) bf16_t Pb[4 * 16 * KBLK];   // 4KB

    const int tid = threadIdx.x;
    const int w = tid >> 6, l = tid & 63;
    const int lo = l & 15, g = l >> 4;

    const int bid = blockIdx.x;
    int b, qt, s_idx;
    if (S == 2) {
        s_idx = bid & 1;
        int qbid = bid >> 1;
        b  = (qbid >> 1) & 3;
        qt = (qbid >> 3) | ((qbid & 1) << 5);
    } else {
        s_idx = 0;
        b  = (bid >> 1) & 3;
        qt = (bid >> 3) | ((bid & 1) << 5);
    }
    const int kt0 = s_idx * TPS;

    const char* xnb  = (const char*)xn;
    const char* xvTb = (const char*)xvT;
    char* Ksb = (char*)Ks;
    char* VLb = (char*)VL;
    bf16_t* Pw = Pb + w * 16 * KBLK;

    // --- Q fragments (rows qt*64 + w*16 + lo), 12 chunks of K=32 ---
    const size_t qrow = (size_t)b * NN + (size_t)qt * 64 + w * 16 + lo;
    const bf16_t* qp = xn + qrow * DD + g * 8;
    bf16x8 qf[12];
#pragma unroll
    for (int c = 0; c < 12; ++c) qf[c] = *(const bf16x8*)(qp + c * 32);

    const f32x4 fzero = {0.f, 0.f, 0.f, 0.f};
    f32x4 O[24];
#pragma unroll
    for (int i = 0; i < 24; ++i) O[i] = fzero;
    float lacc[4] = {0.f, 0.f, 0.f, 0.f};

#define STAGE_K(KT, BUF) { \
    const size_t kg = ((size_t)b * NN + (size_t)(KT) * KBLK) * (DD * 2); \
    char* kdst = Ksb + (BUF) * 24576; \
    _Pragma("unroll") \
    for (int i = 0; i < 6; ++i) { \
        int ci = i * 256 + tid; int key = ci & 31; int cg = ci >> 5; \
        load_lds16(xnb + kg + (size_t)key * (DD * 2) + cg * 16, \
                   (void*)(kdst + (size_t)(i * 256 + (w << 6)) * 16)); \
    } }

#define STAGE_V(KT) { \
    const size_t vg = (size_t)b * ((size_t)DD * NN * 2) + (size_t)(KT) * (KBLK * 2); \
    _Pragma("unroll") \
    for (int i = 0; i < 6; ++i) { \
        int ci = i * 256 + tid; int lo4 = ci & 15; int g4v = (ci >> 4) & 3; int dtv = ci >> 6; \
        load_lds16(xvTb + vg + (size_t)(dtv * 16 + lo4) * (NN * 2) + g4v * 16, \
                   (void*)(VLb + (size_t)(i * 256 + (w << 6)) * 16)); \
    } }

    // prologue: K[kt0] -> buf 0
    STAGE_K(kt0, 0);

    const char* kB  = Ksb + (g << 9) + (lo << 4);   // + p*24576 + c*2048 + nt*256
    const char* vbL = VLb + (g << 8) + (lo << 4);   // + dt*1024
    const bf16_t* pap = Pw + lo * KBLK + g * 8;

    for (int t = 0; t < TPS; ++t) {
        const int kt = kt0 + t;
        const int p = t & 1;

        // --- issue V[t] and K[t+1] (other buffer); nothing drained ---
        STAGE_V(kt);
        __builtin_amdgcn_sched_barrier(0);
        int ktn = kt + 1; if (ktn > NKT - 1) ktn = NKT - 1;
        STAGE_K(ktn, p ^ 1);
        __builtin_amdgcn_sched_barrier(0);

        // --- K[t] ready (waits oldest 6 only; V[t]+K[t+1] stay in flight) ---
        asm volatile("s_waitcnt vmcnt(12)" ::: "memory");
        __builtin_amdgcn_sched_barrier(0);
        __builtin_amdgcn_s_barrier();
        __builtin_amdgcn_sched_barrier(0);

        // --- QK^T: S[16q x 32k], 24 MFMAs, single dep-chain pair ---
        const char* kb = kB + p * 24576;
        f32x4 s0 = fzero, s1 = fzero;
#pragma unroll
        for (int c = 0; c < 12; ++c) {
            bf16x8 kf0 = *(const bf16x8*)(kb + c * 2048);
            bf16x8 kf1 = *(const bf16x8*)(kb + c * 2048 + 256);
            s0 = __builtin_amdgcn_mfma_f32_16x16x32_bf16(qf[c], kf0, s0, 0, 0, 0);
            s1 = __builtin_amdgcn_mfma_f32_16x16x32_bf16(qf[c], kf1, s1, 0, 0, 0);
        }

        // --- fixed-max softmax; per-lane denominator accumulation ---
        float p0[4], p1[4];
#pragma unroll
        for (int r = 0; r < 4; ++r) {
            p0[r] = __builtin_amdgcn_exp2f(fmaf(s0[r], SCALEC, -SCALEC));
            p1[r] = __builtin_amdgcn_exp2f(fmaf(s1[r], SCALEC, -SCALEC));
            lacc[r] += p0[r] + p1[r];
        }
#pragma unroll
        for (int r = 0; r < 4; ++r) {
            Pw[(g * 4 + r) * KBLK + lo]      = (bf16_t)p0[r];
            Pw[(g * 4 + r) * KBLK + lo + 16] = (bf16_t)p1[r];
        }

        // --- V[t] ready (K[t+1] rides through); P write->read ordered by lgkm ---
        asm volatile("s_waitcnt vmcnt(6) lgkmcnt(0)" ::: "memory");
        __builtin_amdgcn_sched_barrier(0);
        __builtin_amdgcn_s_barrier();
        __builtin_amdgcn_sched_barrier(0);

        bf16x8 pa = *(const bf16x8*)pap;

        // --- PV: 24 MFMAs from VL ---
#pragma unroll
        for (int dt = 0; dt < 24; ++dt) {
            bf16x8 vf = *(const bf16x8*)(vbL + dt * 1024);
            O[dt] = __builtin_amdgcn_mfma_f32_16x16x32_bf16(pa, vf, O[dt], 0, 0, 0);
        }

        // --- end barrier (plain): VL / Ks[p] safe to overwrite next tile ---
        __builtin_amdgcn_sched_barrier(0);
        __builtin_amdgcn_s_barrier();
        __builtin_amdgcn_sched_barrier(0);
    }
#undef STAGE_K
#undef STAGE_V

    // --- denominator: reduce per-lane partials across the 16-lane col group ---
#pragma unroll
    for (int mk = 1; mk < 16; mk <<= 1) {
#pragma unroll
        for (int r = 0; r < 4; ++r) lacc[r] += __shfl_xor(lacc[r], mk);
    }
    const int orow0 = b * NN + qt * 64 + w * 16;
    if (DIRECT) {
        float inv[4];
#pragma unroll
        for (int r = 0; r < 4; ++r) inv[r] = 0.3f / lacc[r];
#pragma unroll
        for (int dt = 0; dt < 24; ++dt) {
#pragma unroll
            for (int r = 0; r < 4; ++r) {
                size_t idx = (size_t)(orow0 + g * 4 + r) * DD + dt * 16 + lo;
                out[idx] = x[idx] + O[dt][r] * inv[r];
            }
        }
    } else {
        if (lo == 0) {
#pragma unroll
            for (int r = 0; r < 4; ++r)
                lpart[(size_t)s_idx * NROWS + orow0 + g * 4 + r] = lacc[r];
        }
        float* Ob = Opart + (size_t)s_idx * NROWS * DD;
#pragma unroll
        for (int dt = 0; dt < 24; ++dt) {
#pragma unroll
            for (int r = 0; r < 4; ++r) {
                Ob[(size_t)(orow0 + g * 4 + r) * DD + dt * 16 + lo] = O[dt][r];
            }
        }
    }
}

// ---------------- Kernel 4: merge 2 splits + residual ----------------
__global__ __launch_bounds__(256) void merge_kernel(const float* __restrict__ x,
                                                    const float* __restrict__ Opart,
                                                    const float* __restrict__ lpart,
                                                    float* __restrict__ out) {
    int row  = blockIdx.x * 4 + (threadIdx.x >> 6);
    int lane = threadIdx.x & 63;
    float lsum = lpart[row] + lpart[NROWS + row];
    float inv = 0.3f / lsum;
    size_t base = (size_t)row * DD;
    const float* O0 = Opart + base;
    const float* O1 = Opart + (size_t)NROWS * DD + base;
#pragma unroll
    for (int j = 0; j < 6; ++j) {
        int d = lane + j * 64;
        out[base + d] = x[base + d] + (O0[d] + O1[d]) * inv;
    }
}

extern "C" void kernel_launch(void* const* d_in, const int* in_sizes, int n_in,
                              void* d_out, int out_size, void* d_ws, size_t ws_size,
                              hipStream_t stream) {
    const float* x = (const float*)d_in[0];
    float* out = (float*)d_out;
    char* ws = (char*)d_ws;

    const size_t xn_bytes = (size_t)BB * NN * DD * 2;           // 12.58 MB
    bf16_t* xn  = (bf16_t*)ws;
    bf16_t* xvT = (bf16_t*)(ws + xn_bytes);
    float* Opart = (float*)(ws + 2 * xn_bytes);
    const size_t Opart_bytes = (size_t)2 * NROWS * DD * 4;      // 50.3 MB
    float* lpart = (float*)(ws + 2 * xn_bytes + Opart_bytes);
    const size_t need2 = 2 * xn_bytes + Opart_bytes + (size_t)2 * NROWS * 4;

    norm_kernel<<<(BB * NN) / 4, 256, 0, stream>>>(x, xn);
    transpose_kernel<<<BB * (NN / 64) * (DD / 64), 256, 0, stream>>>(x, xvT);
    if (ws_size >= need2) {
        attn_kernel<2, false><<<512, 256, 0, stream>>>(x, xn, xvT, out, Opart, lpart);
        merge_kernel<<<NROWS / 4, 256, 0, stream>>>(x, Opart, lpart, out);
    } else {
        attn_kernel<1, true><<<256, 256, 0, stream>>>(x, xn, xvT, out, nullptr, nullptr);
    }
}